// Round 2
// baseline (167.663 us; speedup 1.0000x reference)
//
#include <hip/hip_runtime.h>

// WindowOverlapProcessor — gather formulation, 8-pixel stride cell per thread.
// Regular grid (stride 8, win 16): output cell [8tw, 8tw+8) x row h is covered
// by windows j in {tw-1, tw} and i in {floor((h-8)/8), floor(h/8)} (clamped).
// Each covering window contributes one contiguous 24-float (96 B, 16 B-aligned)
// row segment -> 6x float4 loads. Weight denom is separable: hsum * wk[k].
// Traffic: 97.5 MB read (exactly once) + 25.2 MB write ~ 19.5 us floor.

#define OH 512
#define OW 512
#define NB 8
#define NC 3
#define WSZ 16
#define STR 8
#define HWIN 63
#define NWIN (63 * 63)

__global__ __launch_bounds__(256) void window_overlap_kernel(
    const float* __restrict__ win, float* __restrict__ out) {
    // normalized gaussian blend g[16] in LDS (sigma = 16/4 = 4)
    __shared__ float gs[16];
    const int tid = threadIdx.x;
    if (tid < 16) {
        float x = (float)tid - 7.5f;
        gs[tid] = expf(-(x * x) * (1.0f / 32.0f));
    }
    __syncthreads();
    if (tid == 0) {
        float s = 0.0f;
#pragma unroll
        for (int i = 0; i < 16; ++i) s += gs[i];
        float inv = 1.0f / s;
#pragma unroll
        for (int i = 0; i < 16; ++i) gs[i] *= inv;
    }
    __syncthreads();

    const int idx = blockIdx.x * 256 + tid;  // B * H * (W/8) = 262144 threads
    const int tw = idx & 63;                 // w-cell index, w0 = 8*tw
    const int h  = (idx >> 6) & (OH - 1);
    const int b  = idx >> 15;
    const int w0 = tw * STR;

    const int ilo = max((h - 8) >> 3, 0);
    const int ihi = min(h >> 3, HWIN - 1);
    const int jlo = max(tw - 1, 0);
    const int jhi = min(tw, HWIN - 1);

    float acc0[8], acc1[8], acc2[8], wk[8];
#pragma unroll
    for (int k = 0; k < 8; ++k) { acc0[k] = acc1[k] = acc2[k] = wk[k] = 0.0f; }

    float hsum = 0.0f;
    for (int i = ilo; i <= ihi; ++i) hsum += gs[h - i * STR];

    for (int j = jlo; j <= jhi; ++j) {
        const int dw0 = (tw - j) * STR;      // 0 or 8
        float gw[8];
#pragma unroll
        for (int k = 0; k < 8; ++k) { gw[k] = gs[dw0 + k]; wk[k] += gw[k]; }

        for (int i = ilo; i <= ihi; ++i) {
            const int dh = h - i * STR;
            const float gh = gs[dh];
            const float* p = win +
                (size_t)(((b * NWIN + i * HWIN + j) * (WSZ * WSZ) + dh * WSZ + dw0) * NC);
            // 24 contiguous floats, 16 B-aligned: 6x dwordx4
            float vals[24];
            const float4* p4 = (const float4*)p;
            float4* v4 = (float4*)vals;
            v4[0] = p4[0]; v4[1] = p4[1]; v4[2] = p4[2];
            v4[3] = p4[3]; v4[4] = p4[4]; v4[5] = p4[5];
#pragma unroll
            for (int k = 0; k < 8; ++k) {
                const float g = gh * gw[k];
                acc0[k] += g * vals[k * 3 + 0];
                acc1[k] += g * vals[k * 3 + 1];
                acc2[k] += g * vals[k * 3 + 2];
            }
        }
    }

    float r[8];
#pragma unroll
    for (int k = 0; k < 8; ++k) r[k] = 1.0f / (hsum * wk[k] + 1e-8f);

    float* ob = out + (size_t)b * NC * (OH * OW) + h * OW + w0;
    {
        float4 o;
        float4* q = (float4*)ob;
        o = make_float4(acc0[0]*r[0], acc0[1]*r[1], acc0[2]*r[2], acc0[3]*r[3]); q[0] = o;
        o = make_float4(acc0[4]*r[4], acc0[5]*r[5], acc0[6]*r[6], acc0[7]*r[7]); q[1] = o;
        q = (float4*)(ob + OH * OW);
        o = make_float4(acc1[0]*r[0], acc1[1]*r[1], acc1[2]*r[2], acc1[3]*r[3]); q[0] = o;
        o = make_float4(acc1[4]*r[4], acc1[5]*r[5], acc1[6]*r[6], acc1[7]*r[7]); q[1] = o;
        q = (float4*)(ob + 2 * OH * OW);
        o = make_float4(acc2[0]*r[0], acc2[1]*r[1], acc2[2]*r[2], acc2[3]*r[3]); q[0] = o;
        o = make_float4(acc2[4]*r[4], acc2[5]*r[5], acc2[6]*r[6], acc2[7]*r[7]); q[1] = o;
    }
}

extern "C" void kernel_launch(void* const* d_in, const int* in_sizes, int n_in,
                              void* d_out, int out_size, void* d_ws, size_t ws_size,
                              hipStream_t stream) {
    const float* windows = (const float*)d_in[0];
    float* out = (float*)d_out;
    const int total = NB * OH * (OW / STR);  // 262144 threads
    window_overlap_kernel<<<total / 256, 256, 0, stream>>>(windows, out);
}

// Round 3
// 160.714 us; speedup vs baseline: 1.0432x; 1.0432x over previous
//
#include <hip/hip_runtime.h>

// WindowOverlapProcessor — gather, one thread per output pixel (dense wave
// access), branch-free 2x2 covering-window structure.
//
// Regular grid (stride 8, win 16): pixel (h,w) is covered by windows
// i in {i1-1, i1}, j in {j1-1, j1} with i1=min(h>>3,62), clamped at the
// borders; invalid combos get weight 0 (indices clamped so loads stay
// in-bounds). Weight denom is separable: (gh0+gh1)*(gw0+gw1).
//
// Access pattern: lanes = consecutive w -> per-lane 12 B contiguous triples,
// 768 B dense per wave per window (global_load_dwordx3); stores are 3 dense
// dword planes. Each input element is read exactly once.
// Traffic: 97.5 MB read + 25.2 MB write -> ~19.5 us floor at 6.3 TB/s.

#define OH 512
#define OW 512
#define NB 8
#define NC 3
#define WSZ 16
#define STR 8
#define HWIN 63
#define NWIN (HWIN * HWIN)

struct F3 { float x, y, z; };

__global__ __launch_bounds__(256) void window_overlap_kernel(
    const float* __restrict__ win, float* __restrict__ out) {
    // normalized gaussian blend g[16] (sigma = 4)
    __shared__ float gs[16];
    const int tid = threadIdx.x;
    if (tid < 16) {
        float x = (float)tid - 7.5f;
        gs[tid] = expf(-(x * x) * (1.0f / 32.0f));
    }
    __syncthreads();
    if (tid == 0) {
        float s = 0.0f;
#pragma unroll
        for (int i = 0; i < 16; ++i) s += gs[i];
        float inv = 1.0f / s;
#pragma unroll
        for (int i = 0; i < 16; ++i) gs[i] *= inv;
    }
    __syncthreads();

    const int idx = blockIdx.x * 256 + tid;  // B*H*W threads, lane = w
    const int w = idx & (OW - 1);
    const int h = (idx >> 9) & (OH - 1);
    const int b = idx >> 18;

    // vertical covering windows: i1 (always valid), i0 = i1-1 (maybe)
    const int i1 = min(h >> 3, HWIN - 1);
    const int dh1 = h - i1 * STR;                 // in [0,16)
    const int i0 = max(i1 - 1, 0);
    const int dh0 = min(h - i0 * STR, 15);        // clamped; weight 0 if invalid
    const float gh1 = gs[dh1];
    const float gh0 = (i1 >= 1 && dh1 <= 7) ? gs[dh0] : 0.0f;

    const int j1 = min(w >> 3, HWIN - 1);
    const int dw1 = w - j1 * STR;
    const int j0 = max(j1 - 1, 0);
    const int dw0 = min(w - j0 * STR, 15);
    const float gw1 = gs[dw1];
    const float gw0 = (j1 >= 1 && dw1 <= 7) ? gs[dw0] : 0.0f;

    // pixel indices into windows[b, n, dh, dw, :] (F3 granularity)
    const F3* __restrict__ wp = (const F3*)win;
    const size_t bb = (size_t)b * NWIN * (WSZ * WSZ);
    const size_t p00 = bb + (size_t)(i0 * HWIN + j0) * (WSZ * WSZ) + dh0 * WSZ + dw0;
    const size_t p01 = bb + (size_t)(i0 * HWIN + j1) * (WSZ * WSZ) + dh0 * WSZ + dw1;
    const size_t p10 = bb + (size_t)(i1 * HWIN + j0) * (WSZ * WSZ) + dh1 * WSZ + dw0;
    const size_t p11 = bb + (size_t)(i1 * HWIN + j1) * (WSZ * WSZ) + dh1 * WSZ + dw1;

    const F3 v00 = wp[p00];
    const F3 v01 = wp[p01];
    const F3 v10 = wp[p10];
    const F3 v11 = wp[p11];

    const float g00 = gh0 * gw0, g01 = gh0 * gw1;
    const float g10 = gh1 * gw0, g11 = gh1 * gw1;

    const float ax = g00 * v00.x + g01 * v01.x + g10 * v10.x + g11 * v11.x;
    const float ay = g00 * v00.y + g01 * v01.y + g10 * v10.y + g11 * v11.y;
    const float az = g00 * v00.z + g01 * v01.z + g10 * v10.z + g11 * v11.z;

    const float wsum = (gh0 + gh1) * (gw0 + gw1);
    const float r = 1.0f / (wsum + 1e-8f);

    const size_t p = (size_t)b * NC * (OH * OW) + h * OW + w;
    out[p] = ax * r;
    out[p + OH * OW] = ay * r;
    out[p + 2 * (OH * OW)] = az * r;
}

extern "C" void kernel_launch(void* const* d_in, const int* in_sizes, int n_in,
                              void* d_out, int out_size, void* d_ws, size_t ws_size,
                              hipStream_t stream) {
    const float* windows = (const float*)d_in[0];
    float* out = (float*)d_out;
    const int total = NB * OH * OW;  // 2,097,152 threads
    window_overlap_kernel<<<total / 256, 256, 0, stream>>>(windows, out);
}